// Round 5
// baseline (380.989 us; speedup 1.0000x reference)
//
#include <hip/hip_runtime.h>

// Fused transformer block: B=2048, T=128, DM=32, H=2, DK=16.
// Round 5: bisect-by-construction. Only HW-validated circuits:
//   LN1/LN2: per-thread full-row (rounds 1/2)
//   QKV/Wo/FFN: MFMA 16x16x32 bf16, kC-validated store/read patterns (round 2)
//   attention: per-thread VALU causal softmax (round 2 kB), bf16 K/V rows
//
// LDS 53760 B -> 3 blocks/CU:
//   xsf  f32[128][33] 16896B  (x stage -> attn bf16[128][36] -> x2 f32 -> h strips)
//   xlnS bf16[128][36] 9216B
//   qS   bf16[2][128][18] 9216B
//   kS   bf16[2][128][18] 9216B  (-> x3 bf16[128][36] after attention)
//   vS   bf16[2][128][18] 9216B

typedef __attribute__((ext_vector_type(8))) short short8x;
typedef __attribute__((ext_vector_type(4))) float f32x4;

__device__ __forceinline__ unsigned short f2bf(float f) {
    union { float f; unsigned u; } c; c.f = f;
    return (unsigned short)((c.u + 0x7FFFu + ((c.u >> 16) & 1u)) >> 16);
}
__device__ __forceinline__ float bf2f(unsigned short s) {
    union { unsigned u; float f; } c; c.u = ((unsigned)s) << 16;
    return c.f;
}
__device__ __forceinline__ float bflo(unsigned u) { union { unsigned x; float f; } c; c.x = u << 16; return c.f; }
__device__ __forceinline__ float bfhi(unsigned u) { union { unsigned x; float f; } c; c.x = u & 0xFFFF0000u; return c.f; }

// ---------------------------------------------------------------- setup
// 24 frags x 64 lanes x 16B. elem j of lane l: k=(j&3)+4*(l>>4)+16*(j>>2), n=l&15.
// f 0..5: QKV-B (mat=f>>1, h=f&1); 6..7: Wo-B; 8..15: W1-B; 16..23: W2-B.
__global__ void setup_frags(const float* __restrict__ Wq, const float* __restrict__ Wk,
                            const float* __restrict__ Wv, const float* __restrict__ Wo,
                            const float* __restrict__ W1, const float* __restrict__ W2,
                            uint4* __restrict__ F)
{
    const int g = blockIdx.x * 256 + threadIdx.x;
    if (g >= 1536) return;
    const int f = g >> 6, l = g & 63;
    const int ln = l & 15, g4 = l >> 4;
    unsigned short e[8];
    #pragma unroll
    for (int j = 0; j < 8; ++j) {
        const int k = (j & 3) + 4 * g4 + 16 * (j >> 2);
        float v;
        if (f < 6) {
            const int mat = f >> 1, h = f & 1;
            const float* W = (mat == 0) ? Wq : (mat == 1 ? Wk : Wv);
            v = W[h * 512 + k * 16 + ln];
        } else if (f < 8) {
            v = Wo[k * 32 + (f - 6) * 16 + ln];
        } else if (f < 16) {
            v = W1[k * 128 + (f - 8) * 16 + ln];
        } else {
            const int idx = f - 16, nt2 = idx >> 2, kc = idx & 3;
            v = W2[(32 * kc + k) * 32 + nt2 * 16 + ln];
        }
        e[j] = f2bf(v);
    }
    uint4 o;
    o.x = (unsigned)e[0] | ((unsigned)e[1] << 16);
    o.y = (unsigned)e[2] | ((unsigned)e[3] << 16);
    o.z = (unsigned)e[4] | ((unsigned)e[5] << 16);
    o.w = (unsigned)e[6] | ((unsigned)e[7] << 16);
    F[g] = o;
}

// ---------------------------------------------------------------- main
__global__ __launch_bounds__(256, 3) void fused_block(
    const float* __restrict__ x, const float* __restrict__ bo,
    const float* __restrict__ b1, const float* __restrict__ b2,
    const float* __restrict__ g1, const float* __restrict__ be1,
    const float* __restrict__ g2, const float* __restrict__ be2,
    const uint4* __restrict__ F, float* __restrict__ out)
{
    __shared__ float xsf[4224];
    __shared__ unsigned short xlnS[4608];
    __shared__ unsigned short qS[4608];
    __shared__ unsigned short kS[4608];
    __shared__ unsigned short vS[4608];

    const int tid = threadIdx.x;
    const int lane = tid & 63, w = tid >> 6;
    const int ln = lane & 15, g4 = lane >> 4;
    const size_t blk = blockIdx.x;

    // ---- phase 0: stage x (coalesced float4)
    {
        const float4* xg = reinterpret_cast<const float4*>(x + blk * 4096);
        #pragma unroll
        for (int i = 0; i < 4; ++i) {
            const int o = i * 256 + tid;
            const float4 v = xg[o];
            const int r = o >> 3, c = (o & 7) * 4;
            float* p = xsf + r * 33 + c;
            p[0] = v.x; p[1] = v.y; p[2] = v.z; p[3] = v.w;
        }
    }
    __syncthreads();

    // ---- phase 1: LN1, per-thread full row (validated round 1/2)
    if (tid < 128) {
        const float* row = xsf + tid * 33;
        float s = 0.f, s2 = 0.f;
        #pragma unroll
        for (int m = 0; m < 32; ++m) { const float v = row[m]; s += v; s2 = fmaf(v, v, s2); }
        const float mu  = s * 0.03125f;
        const float inv = rsqrtf(s2 * 0.03125f - mu * mu + 1e-5f);
        #pragma unroll
        for (int m = 0; m < 32; ++m)
            xlnS[tid * 36 + m] = f2bf((row[m] - mu) * inv * g1[m] + be1[m]);
    }
    __syncthreads();

    // ---- phase 2: QKV via MFMA (kC-validated A-read + frag-B pattern)
    {
        short8x bf[6];
        #pragma unroll
        for (int f = 0; f < 6; ++f) {
            union { uint4 q_; short8x s_; } uu; uu.q_ = F[f * 64 + lane]; bf[f] = uu.s_;
        }
        #pragma unroll
        for (int mi = 0; mi < 2; ++mi) {
            const int mt = w + mi * 4;
            union { unsigned u[4]; short8x s_; } xa;
            const char* ab = (const char*)xlnS + (16 * mt + ln) * 72 + 8 * g4;
            xa.u[0] = *(const unsigned*)(ab);
            xa.u[1] = *(const unsigned*)(ab + 4);
            xa.u[2] = *(const unsigned*)(ab + 32);
            xa.u[3] = *(const unsigned*)(ab + 36);
            #pragma unroll
            for (int f = 0; f < 6; ++f) {
                f32x4 z = {0.f, 0.f, 0.f, 0.f};
                const f32x4 c = __builtin_amdgcn_mfma_f32_16x16x32_bf16(xa.s_, bf[f], z, 0, 0, 0);
                const int mat = f >> 1, h = f & 1;
                unsigned short* dst = (mat == 0 ? qS : (mat == 1 ? kS : vS)) + h * 2304;
                #pragma unroll
                for (int r = 0; r < 4; ++r)
                    dst[(16 * mt + 4 * g4 + r) * 18 + ln] = f2bf(c[r]);
            }
        }
    }
    __syncthreads();

    // ---- phase 3: per-thread VALU causal attention (round-2 kB circuit)
    {
        const int h = tid >> 7, t = tid & 127;
        const char* qrow = (const char*)qS + h * 4608 + t * 36;
        float q[16];
        {
            const uint2 a = *(const uint2*)(qrow);
            const uint2 b = *(const uint2*)(qrow + 8);
            const uint2 c = *(const uint2*)(qrow + 16);
            const uint2 d = *(const uint2*)(qrow + 24);
            q[0]=bflo(a.x);  q[1]=bfhi(a.x);  q[2]=bflo(a.y);  q[3]=bfhi(a.y);
            q[4]=bflo(b.x);  q[5]=bfhi(b.x);  q[6]=bflo(b.y);  q[7]=bfhi(b.y);
            q[8]=bflo(c.x);  q[9]=bfhi(c.x);  q[10]=bflo(c.y); q[11]=bfhi(c.y);
            q[12]=bflo(d.x); q[13]=bfhi(d.x); q[14]=bflo(d.y); q[15]=bfhi(d.y);
        }
        const char* kb = (const char*)kS + h * 4608;
        const char* vb = (const char*)vS + h * 4608;
        float acc[16];
        #pragma unroll
        for (int i = 0; i < 16; ++i) acc[i] = 0.f;
        float lsum = 0.f;
        for (int s = 0; s <= t; ++s) {
            const uint2 ka = *(const uint2*)(kb + s * 36);
            const uint2 k2 = *(const uint2*)(kb + s * 36 + 8);
            const uint2 k3 = *(const uint2*)(kb + s * 36 + 16);
            const uint2 k4 = *(const uint2*)(kb + s * 36 + 24);
            float sc;
            sc = q[0] * bflo(ka.x);
            sc = fmaf(q[1],  bfhi(ka.x), sc);
            sc = fmaf(q[2],  bflo(ka.y), sc);
            sc = fmaf(q[3],  bfhi(ka.y), sc);
            sc = fmaf(q[4],  bflo(k2.x), sc);
            sc = fmaf(q[5],  bfhi(k2.x), sc);
            sc = fmaf(q[6],  bflo(k2.y), sc);
            sc = fmaf(q[7],  bfhi(k2.y), sc);
            sc = fmaf(q[8],  bflo(k3.x), sc);
            sc = fmaf(q[9],  bfhi(k3.x), sc);
            sc = fmaf(q[10], bflo(k3.y), sc);
            sc = fmaf(q[11], bfhi(k3.y), sc);
            sc = fmaf(q[12], bflo(k4.x), sc);
            sc = fmaf(q[13], bfhi(k4.x), sc);
            sc = fmaf(q[14], bflo(k4.y), sc);
            sc = fmaf(q[15], bfhi(k4.y), sc);
            const float p = __expf(sc);
            lsum += p;
            const uint2 va = *(const uint2*)(vb + s * 36);
            const uint2 v2 = *(const uint2*)(vb + s * 36 + 8);
            const uint2 v3 = *(const uint2*)(vb + s * 36 + 16);
            const uint2 v4 = *(const uint2*)(vb + s * 36 + 24);
            acc[0]  = fmaf(p, bflo(va.x), acc[0]);
            acc[1]  = fmaf(p, bfhi(va.x), acc[1]);
            acc[2]  = fmaf(p, bflo(va.y), acc[2]);
            acc[3]  = fmaf(p, bfhi(va.y), acc[3]);
            acc[4]  = fmaf(p, bflo(v2.x), acc[4]);
            acc[5]  = fmaf(p, bfhi(v2.x), acc[5]);
            acc[6]  = fmaf(p, bflo(v2.y), acc[6]);
            acc[7]  = fmaf(p, bfhi(v2.y), acc[7]);
            acc[8]  = fmaf(p, bflo(v3.x), acc[8]);
            acc[9]  = fmaf(p, bfhi(v3.x), acc[9]);
            acc[10] = fmaf(p, bflo(v3.y), acc[10]);
            acc[11] = fmaf(p, bfhi(v3.y), acc[11]);
            acc[12] = fmaf(p, bflo(v4.x), acc[12]);
            acc[13] = fmaf(p, bfhi(v4.x), acc[13]);
            acc[14] = fmaf(p, bflo(v4.y), acc[14]);
            acc[15] = fmaf(p, bfhi(v4.y), acc[15]);
        }
        const float linv = 1.f / lsum;
        unsigned short* attnS = reinterpret_cast<unsigned short*>(xsf);
        #pragma unroll
        for (int i = 0; i < 16; ++i)
            attnS[t * 36 + 16 * h + i] = f2bf(acc[i] * linv);
    }
    __syncthreads();

    // ---- phase 4: x2 = xln + attn @ Wo + bo (MFMA), x2 -> xsf f32
    {
        short8x wb0, wb1;
        { union { uint4 q_; short8x s_; } uu; uu.q_ = F[6 * 64 + lane]; wb0 = uu.s_; }
        { union { uint4 q_; short8x s_; } uu; uu.q_ = F[7 * 64 + lane]; wb1 = uu.s_; }
        const unsigned short* attnS = reinterpret_cast<const unsigned short*>(xsf);
        f32x4 c0[2], c1[2];
        #pragma unroll
        for (int mi = 0; mi < 2; ++mi) {
            const int mt = w + mi * 4;
            union { unsigned u[4]; short8x s_; } af;
            const char* ab = (const char*)attnS + (16 * mt + ln) * 72 + 8 * g4;
            af.u[0] = *(const unsigned*)(ab);
            af.u[1] = *(const unsigned*)(ab + 4);
            af.u[2] = *(const unsigned*)(ab + 32);
            af.u[3] = *(const unsigned*)(ab + 36);
            f32x4 z = {0.f, 0.f, 0.f, 0.f};
            c0[mi] = __builtin_amdgcn_mfma_f32_16x16x32_bf16(af.s_, wb0, z, 0, 0, 0);
            c1[mi] = __builtin_amdgcn_mfma_f32_16x16x32_bf16(af.s_, wb1, z, 0, 0, 0);
        }
        __syncthreads();   // all attnS reads complete before xsf overwrite
        const float bo0 = bo[ln], bo1 = bo[16 + ln];
        #pragma unroll
        for (int mi = 0; mi < 2; ++mi) {
            const int mt = w + mi * 4;
            #pragma unroll
            for (int r = 0; r < 4; ++r) {
                const int row = 16 * mt + 4 * g4 + r;
                xsf[row * 33 + ln]      = c0[mi][r] + bo0 + bf2f(xlnS[row * 36 + ln]);
                xsf[row * 33 + 16 + ln] = c1[mi][r] + bo1 + bf2f(xlnS[row * 36 + 16 + ln]);
            }
        }
    }
    __syncthreads();

    // ---- phase 5: LN2, per-thread full row -> x3 bf16 into kS region
    if (tid < 128) {
        const float* row = xsf + tid * 33;
        float s = 0.f, s2 = 0.f;
        #pragma unroll
        for (int m = 0; m < 32; ++m) { const float v = row[m]; s += v; s2 = fmaf(v, v, s2); }
        const float mu  = s * 0.03125f;
        const float inv = rsqrtf(s2 * 0.03125f - mu * mu + 1e-5f);
        #pragma unroll
        for (int m = 0; m < 32; ++m)
            kS[tid * 36 + m] = f2bf((row[m] - mu) * inv * g2[m] + be2[m]);
    }
    __syncthreads();

    // ---- phase 6: FFN via per-wave h strip (round-2 kC circuit) + residual
    {
        unsigned short* hs = reinterpret_cast<unsigned short*>(xsf) + w * 2112;
        float b1v[8];
        #pragma unroll
        for (int nt = 0; nt < 8; ++nt) b1v[nt] = b1[nt * 16 + ln];
        const float b2v0 = b2[ln], b2v1 = b2[16 + ln];
        #pragma unroll
        for (int ti = 0; ti < 2; ++ti) {
            const int tt = w + ti * 4;
            union { unsigned u[4]; short8x s_; } xf;
            const char* xb = (const char*)kS + (16 * tt + ln) * 72 + 8 * g4;
            xf.u[0] = *(const unsigned*)(xb);
            xf.u[1] = *(const unsigned*)(xb + 4);
            xf.u[2] = *(const unsigned*)(xb + 32);
            xf.u[3] = *(const unsigned*)(xb + 36);
            asm volatile("s_waitcnt lgkmcnt(0)" ::: "memory");
            #pragma unroll
            for (int nt = 0; nt < 8; ++nt) {
                union { uint4 q_; short8x s_; } wf; wf.q_ = F[(8 + nt) * 64 + lane];
                f32x4 z = {0.f, 0.f, 0.f, 0.f};
                const f32x4 c = __builtin_amdgcn_mfma_f32_16x16x32_bf16(xf.s_, wf.s_, z, 0, 0, 0);
                #pragma unroll
                for (int rq = 0; rq < 4; ++rq)
                    hs[(4 * g4 + rq) * 132 + nt * 16 + ln] = f2bf(fmaxf(c[rq] + b1v[nt], 0.f));
            }
            asm volatile("s_waitcnt lgkmcnt(0)" ::: "memory");
            #pragma unroll
            for (int nt2 = 0; nt2 < 2; ++nt2) {
                f32x4 a = {0.f, 0.f, 0.f, 0.f};
                #pragma unroll
                for (int kq = 0; kq < 4; ++kq) {
                    union { unsigned u[4]; short8x s_; } pa;
                    const char* pb = (const char*)hs + ln * 264 + 64 * kq + 8 * g4;
                    *reinterpret_cast<uint2*>(&pa.u[0]) = *(const uint2*)(pb);
                    *reinterpret_cast<uint2*>(&pa.u[2]) = *(const uint2*)(pb + 32);
                    union { uint4 q_; short8x s_; } w2f; w2f.q_ = F[(16 + nt2 * 4 + kq) * 64 + lane];
                    a = __builtin_amdgcn_mfma_f32_16x16x32_bf16(pa.s_, w2f.s_, a, 0, 0, 0);
                }
                #pragma unroll
                for (int r = 0; r < 4; ++r) {
                    const int t = 16 * tt + 4 * g4 + r, col = nt2 * 16 + ln;
                    out[(blk * 128 + t) * 32 + col] =
                        a[r] + (nt2 ? b2v1 : b2v0) + bf2f(kS[t * 36 + col]);
                }
            }
        }
    }
}

// ---------------------------------------------------------------- launch
extern "C" void kernel_launch(void* const* d_in, const int* in_sizes, int n_in,
                              void* d_out, int out_size, void* d_ws, size_t ws_size,
                              hipStream_t stream) {
    const float* x   = (const float*)d_in[0];
    const float* Wq  = (const float*)d_in[1];
    const float* Wk  = (const float*)d_in[2];
    const float* Wv  = (const float*)d_in[3];
    const float* Wo  = (const float*)d_in[4];
    const float* bo  = (const float*)d_in[5];
    const float* W1  = (const float*)d_in[6];
    const float* b1  = (const float*)d_in[7];
    const float* W2  = (const float*)d_in[8];
    const float* b2  = (const float*)d_in[9];
    const float* g1  = (const float*)d_in[10];
    const float* be1 = (const float*)d_in[11];
    const float* g2  = (const float*)d_in[12];
    const float* be2 = (const float*)d_in[13];
    float* outp = (float*)d_out;
    uint4* F = (uint4*)d_ws;

    hipLaunchKernelGGL(setup_frags, dim3(6), dim3(256), 0, stream,
                       Wq, Wk, Wv, Wo, W1, W2, F);
    hipLaunchKernelGGL(fused_block, dim3(2048), dim3(256), 0, stream,
                       x, bo, b1, b2, g1, be1, g2, be2, F, outp);
}

// Round 6
// 142.611 us; speedup vs baseline: 2.6715x; 2.6715x over previous
//
#include <hip/hip_runtime.h>

// Fused transformer block: B=2048, T=128, DM=32, H=2, DK=16.
// Round 6 = round-5 proven skeleton + strip-based MFMA attention with
// kC-style fence discipline (lgkmcnt(0)+sched_barrier between strip
// read/write groups) and type-matched strip accesses (no TBAA hole).
//
// LDS 52992 B -> 3 blocks/CU:
//   xsf  f32[128][33] 16896B (x -> P strips 4x[16][132] -> x2 f32 -> h strips)
//   xlnS bf16[128][36] 9216B
//   qS   bf16 q[2][128][18] -> attn[128][36] 9216B
//   kS   bf16 k[2][128][18] -> x3[128][36]   9216B
//   vtS  bf16 [2][16][132] 8448B  (V transposed [h][d][t])

typedef __attribute__((ext_vector_type(8))) short short8x;
typedef __attribute__((ext_vector_type(4))) float f32x4;

__device__ __forceinline__ unsigned short f2bf(float f) {
    union { float f; unsigned u; } c; c.f = f;
    return (unsigned short)((c.u + 0x7FFFu + ((c.u >> 16) & 1u)) >> 16);
}
__device__ __forceinline__ float bf2f(unsigned short s) {
    union { unsigned u; float f; } c; c.u = ((unsigned)s) << 16;
    return c.f;
}
__device__ __forceinline__ unsigned packbf(float a, float b) {
    return (unsigned)f2bf(a) | ((unsigned)f2bf(b) << 16);
}

// ---------------------------------------------------------------- setup
// 24 frags x 64 lanes x 16B. elem j of lane l: k=(j&3)+4*(l>>4)+16*(j>>2), n=l&15.
// f 0..5: QKV-B (mat=f>>1, h=f&1); 6..7: Wo-B; 8..15: W1-B; 16..23: W2-B.
__global__ void setup_frags(const float* __restrict__ Wq, const float* __restrict__ Wk,
                            const float* __restrict__ Wv, const float* __restrict__ Wo,
                            const float* __restrict__ W1, const float* __restrict__ W2,
                            uint4* __restrict__ F)
{
    const int g = blockIdx.x * 256 + threadIdx.x;
    if (g >= 1536) return;
    const int f = g >> 6, l = g & 63;
    const int ln = l & 15, g4 = l >> 4;
    unsigned short e[8];
    #pragma unroll
    for (int j = 0; j < 8; ++j) {
        const int k = (j & 3) + 4 * g4 + 16 * (j >> 2);
        float v;
        if (f < 6) {
            const int mat = f >> 1, h = f & 1;
            const float* W = (mat == 0) ? Wq : (mat == 1 ? Wk : Wv);
            v = W[h * 512 + k * 16 + ln];
        } else if (f < 8) {
            v = Wo[k * 32 + (f - 6) * 16 + ln];
        } else if (f < 16) {
            v = W1[k * 128 + (f - 8) * 16 + ln];
        } else {
            const int idx = f - 16, nt2 = idx >> 2, kc = idx & 3;
            v = W2[(32 * kc + k) * 32 + nt2 * 16 + ln];
        }
        e[j] = f2bf(v);
    }
    uint4 o;
    o.x = (unsigned)e[0] | ((unsigned)e[1] << 16);
    o.y = (unsigned)e[2] | ((unsigned)e[3] << 16);
    o.z = (unsigned)e[4] | ((unsigned)e[5] << 16);
    o.w = (unsigned)e[6] | ((unsigned)e[7] << 16);
    F[g] = o;
}

// ---------------------------------------------------------------- attn helper
// One q-tile: S = mfma(Q, K) per k-tile -> S[tq=16QT+4g4+r][tk=16kt+ln];
// mask+exp -> P strip (per-wave LDS), row-sum via 4-bit butterfly,
// PV = mfma(P-strip-A, V^T-B).  Fences: lgkmcnt(0)+sched_barrier before
// the write group AND before the read group (kC-proven pattern).
template<int QT>
__device__ __forceinline__ f32x4 attn_qt(const char* qh, const char* kh, const char* vh,
                                         unsigned short* strip, int ln, int g4)
{
    union { unsigned u[4]; short8x s_; } qf;
    {
        const char* qb = qh + (16 * QT + ln) * 36 + 8 * g4;
        qf.u[0] = *(const unsigned*)(qb);
        qf.u[1] = *(const unsigned*)(qb + 4);
        qf.u[2] = 0; qf.u[3] = 0;                 // dk=16: upper K zero (both operands)
    }
    f32x4 sv[QT + 1];
    #pragma unroll
    for (int kt = 0; kt <= QT; ++kt) {
        union { unsigned u[4]; short8x s_; } kf;
        const char* kb = kh + (16 * kt + ln) * 36 + 8 * g4;
        kf.u[0] = *(const unsigned*)(kb);
        kf.u[1] = *(const unsigned*)(kb + 4);
        kf.u[2] = 0; kf.u[3] = 0;
        f32x4 z = {0.f, 0.f, 0.f, 0.f};
        sv[kt] = __builtin_amdgcn_mfma_f32_16x16x32_bf16(qf.s_, kf.s_, z, 0, 0, 0);
    }
    // order PREVIOUS call's strip reads before THIS call's strip writes
    asm volatile("s_waitcnt lgkmcnt(0)" ::: "memory");
    __builtin_amdgcn_sched_barrier(0);
    float lsum[4] = {0.f, 0.f, 0.f, 0.f};
    #pragma unroll
    for (int kt = 0; kt <= QT; ++kt) {
        #pragma unroll
        for (int r = 0; r < 4; ++r) {
            // S row tq=16QT+4g4+r, col tk=16kt+ln; causal keep tk<=tq
            float e = 0.f;
            if (kt < QT || ln <= 4 * g4 + r) e = __expf(sv[kt][r]);
            strip[(4 * g4 + r) * 132 + 16 * kt + ln] = f2bf(e);
            lsum[r] += e;
        }
    }
    if constexpr ((QT & 1) == 0) {
        // zero-fill pad k-tile so PV's 32-wide reads see zeros
        #pragma unroll
        for (int r = 0; r < 4; ++r)
            strip[(4 * g4 + r) * 132 + 16 * (QT + 1) + ln] = 0;
    }
    #pragma unroll
    for (int r = 0; r < 4; ++r) {
        lsum[r] += __shfl_xor(lsum[r], 1);
        lsum[r] += __shfl_xor(lsum[r], 2);
        lsum[r] += __shfl_xor(lsum[r], 4);
        lsum[r] += __shfl_xor(lsum[r], 8);
    }
    // strip writes complete before strip reads
    asm volatile("s_waitcnt lgkmcnt(0)" ::: "memory");
    __builtin_amdgcn_sched_barrier(0);
    constexpr int NKC = (QT | 1) / 2;
    f32x4 o = {0.f, 0.f, 0.f, 0.f};
    #pragma unroll
    for (int kc = 0; kc <= NKC; ++kc) {
        union { unsigned short e[8]; short8x s_; } pa;   // type-matched with stores
        #pragma unroll
        for (int j = 0; j < 8; ++j)
            pa.e[j] = strip[ln * 132 + 32 * kc + (j & 3) + 4 * g4 + 16 * (j >> 2)];
        union { unsigned u[4]; short8x s_; } vf;         // uint2 store / uint2 read
        const char* vb = vh + ln * 264 + 64 * kc + 8 * g4;
        *reinterpret_cast<uint2*>(&vf.u[0]) = *(const uint2*)(vb);
        *reinterpret_cast<uint2*>(&vf.u[2]) = *(const uint2*)(vb + 32);
        o = __builtin_amdgcn_mfma_f32_16x16x32_bf16(pa.s_, vf.s_, o, 0, 0, 0);
    }
    #pragma unroll
    for (int r = 0; r < 4; ++r) o[r] *= (1.f / lsum[r]);
    return o;   // o[r] = O[tq_local=4g4+r][d=ln]
}

// ---------------------------------------------------------------- main
__global__ __launch_bounds__(256, 3) void fused_block(
    const float* __restrict__ x, const float* __restrict__ bo,
    const float* __restrict__ b1, const float* __restrict__ b2,
    const float* __restrict__ g1, const float* __restrict__ be1,
    const float* __restrict__ g2, const float* __restrict__ be2,
    const uint4* __restrict__ F, float* __restrict__ out)
{
    __shared__ float xsf[4224];
    __shared__ unsigned short xlnS[4608];
    __shared__ unsigned short qS[4608];
    __shared__ unsigned short kS[4608];
    __shared__ unsigned short vtS[4224];

    const int tid = threadIdx.x;
    const int lane = tid & 63, w = tid >> 6;
    const int ln = lane & 15, g4 = lane >> 4;
    const size_t blk = blockIdx.x;

    // ---- phase 0: stage x
    {
        const float4* xg = reinterpret_cast<const float4*>(x + blk * 4096);
        #pragma unroll
        for (int i = 0; i < 4; ++i) {
            const int o = i * 256 + tid;
            const float4 v = xg[o];
            const int r = o >> 3, c = (o & 7) * 4;
            float* p = xsf + r * 33 + c;
            p[0] = v.x; p[1] = v.y; p[2] = v.z; p[3] = v.w;
        }
    }
    __syncthreads();

    // ---- phase 1: LN1, per-thread full row (proven)
    if (tid < 128) {
        const float* row = xsf + tid * 33;
        float s = 0.f, s2 = 0.f;
        #pragma unroll
        for (int m = 0; m < 32; ++m) { const float v = row[m]; s += v; s2 = fmaf(v, v, s2); }
        const float mu  = s * 0.03125f;
        const float inv = rsqrtf(s2 * 0.03125f - mu * mu + 1e-5f);
        #pragma unroll
        for (int m = 0; m < 32; ++m)
            xlnS[tid * 36 + m] = f2bf((row[m] - mu) * inv * g1[m] + be1[m]);
    }
    __syncthreads();

    // ---- phase 2: QKV via MFMA (proven); q,k row-major; v transposed [h][d][t]
    {
        short8x bf[6];
        #pragma unroll
        for (int f = 0; f < 6; ++f) {
            union { uint4 q_; short8x s_; } uu; uu.q_ = F[f * 64 + lane]; bf[f] = uu.s_;
        }
        #pragma unroll
        for (int mi = 0; mi < 2; ++mi) {
            const int mt = w + mi * 4;
            union { unsigned u[4]; short8x s_; } xa;
            const char* ab = (const char*)xlnS + (16 * mt + ln) * 72 + 8 * g4;
            xa.u[0] = *(const unsigned*)(ab);
            xa.u[1] = *(const unsigned*)(ab + 4);
            xa.u[2] = *(const unsigned*)(ab + 32);
            xa.u[3] = *(const unsigned*)(ab + 36);
            #pragma unroll
            for (int f = 0; f < 6; ++f) {
                f32x4 z = {0.f, 0.f, 0.f, 0.f};
                const f32x4 c = __builtin_amdgcn_mfma_f32_16x16x32_bf16(xa.s_, bf[f], z, 0, 0, 0);
                const int mat = f >> 1, h = f & 1;
                if (mat < 2) {
                    unsigned short* dst = (mat == 0 ? qS : kS) + h * 2304;
                    #pragma unroll
                    for (int r = 0; r < 4; ++r)
                        dst[(16 * mt + 4 * g4 + r) * 18 + ln] = f2bf(c[r]);
                } else {
                    char* vb = (char*)vtS + h * 4224 + ln * 264 + 32 * mt + 8 * g4;
                    *reinterpret_cast<uint2*>(vb) =
                        make_uint2(packbf(c[0], c[1]), packbf(c[2], c[3]));
                }
            }
        }
    }
    __syncthreads();

    // ---- phase 3: MFMA attention; O-frags in regs across the barrier
    {
        const int head = w >> 1;
        const char* qh = (const char*)qS  + head * 4608;
        const char* kh = (const char*)kS  + head * 4608;
        const char* vh = (const char*)vtS + head * 4224;
        unsigned short* strip = reinterpret_cast<unsigned short*>(xsf) + w * 2112;
        f32x4 o0, o1, o2, o3;
        if ((w & 1) == 0) {
            o0 = attn_qt<0>(qh, kh, vh, strip, ln, g4);
            o1 = attn_qt<2>(qh, kh, vh, strip, ln, g4);
            o2 = attn_qt<5>(qh, kh, vh, strip, ln, g4);
            o3 = attn_qt<7>(qh, kh, vh, strip, ln, g4);
        } else {
            o0 = attn_qt<1>(qh, kh, vh, strip, ln, g4);
            o1 = attn_qt<3>(qh, kh, vh, strip, ln, g4);
            o2 = attn_qt<4>(qh, kh, vh, strip, ln, g4);
            o3 = attn_qt<6>(qh, kh, vh, strip, ln, g4);
        }
        __syncthreads();                         // all q/k/v reads done
        const int colA = 16 * head + ln;
        #pragma unroll
        for (int r = 0; r < 4; ++r) {
            const int rr = 4 * g4 + r;
            if ((w & 1) == 0) {
                qS[(0   + rr) * 36 + colA] = f2bf(o0[r]);
                qS[(32  + rr) * 36 + colA] = f2bf(o1[r]);
                qS[(80  + rr) * 36 + colA] = f2bf(o2[r]);
                qS[(112 + rr) * 36 + colA] = f2bf(o3[r]);
            } else {
                qS[(16  + rr) * 36 + colA] = f2bf(o0[r]);
                qS[(48  + rr) * 36 + colA] = f2bf(o1[r]);
                qS[(64  + rr) * 36 + colA] = f2bf(o2[r]);
                qS[(96  + rr) * 36 + colA] = f2bf(o3[r]);
            }
        }
    }
    __syncthreads();

    // ---- phase 4: x2 = xln + attn @ Wo + bo (MFMA, attn from qS) -> xsf f32
    {
        short8x wb0, wb1;
        { union { uint4 q_; short8x s_; } uu; uu.q_ = F[6 * 64 + lane]; wb0 = uu.s_; }
        { union { uint4 q_; short8x s_; } uu; uu.q_ = F[7 * 64 + lane]; wb1 = uu.s_; }
        f32x4 c0[2], c1[2];
        #pragma unroll
        for (int mi = 0; mi < 2; ++mi) {
            const int mt = w + mi * 4;
            union { unsigned u[4]; short8x s_; } af;
            const char* ab = (const char*)qS + (16 * mt + ln) * 72 + 8 * g4;
            af.u[0] = *(const unsigned*)(ab);
            af.u[1] = *(const unsigned*)(ab + 4);
            af.u[2] = *(const unsigned*)(ab + 32);
            af.u[3] = *(const unsigned*)(ab + 36);
            f32x4 z = {0.f, 0.f, 0.f, 0.f};
            c0[mi] = __builtin_amdgcn_mfma_f32_16x16x32_bf16(af.s_, wb0, z, 0, 0, 0);
            c1[mi] = __builtin_amdgcn_mfma_f32_16x16x32_bf16(af.s_, wb1, z, 0, 0, 0);
        }
        const float bo0 = bo[ln], bo1 = bo[16 + ln];
        #pragma unroll
        for (int mi = 0; mi < 2; ++mi) {
            const int mt = w + mi * 4;
            #pragma unroll
            for (int r = 0; r < 4; ++r) {
                const int row = 16 * mt + 4 * g4 + r;
                xsf[row * 33 + ln]      = c0[mi][r] + bo0 + bf2f(xlnS[row * 36 + ln]);
                xsf[row * 33 + 16 + ln] = c1[mi][r] + bo1 + bf2f(xlnS[row * 36 + 16 + ln]);
            }
        }
    }
    __syncthreads();

    // ---- phase 5: LN2, per-thread full row (proven) -> x3 bf16 into kS
    if (tid < 128) {
        const float* row = xsf + tid * 33;
        float s = 0.f, s2 = 0.f;
        #pragma unroll
        for (int m = 0; m < 32; ++m) { const float v = row[m]; s += v; s2 = fmaf(v, v, s2); }
        const float mu  = s * 0.03125f;
        const float inv = rsqrtf(s2 * 0.03125f - mu * mu + 1e-5f);
        #pragma unroll
        for (int m = 0; m < 32; ++m)
            kS[tid * 36 + m] = f2bf((row[m] - mu) * inv * g2[m] + be2[m]);
    }
    __syncthreads();

    // ---- phase 6: FFN via per-wave h strip (proven, round-5 verbatim) + residual
    {
        unsigned short* hs = reinterpret_cast<unsigned short*>(xsf) + w * 2112;
        float b1v[8];
        #pragma unroll
        for (int nt = 0; nt < 8; ++nt) b1v[nt] = b1[nt * 16 + ln];
        const float b2v0 = b2[ln], b2v1 = b2[16 + ln];
        #pragma unroll
        for (int ti = 0; ti < 2; ++ti) {
            const int tt = w + ti * 4;
            union { unsigned u[4]; short8x s_; } xf;
            const char* xb = (const char*)kS + (16 * tt + ln) * 72 + 8 * g4;
            xf.u[0] = *(const unsigned*)(xb);
            xf.u[1] = *(const unsigned*)(xb + 4);
            xf.u[2] = *(const unsigned*)(xb + 32);
            xf.u[3] = *(const unsigned*)(xb + 36);
            asm volatile("s_waitcnt lgkmcnt(0)" ::: "memory");
            __builtin_amdgcn_sched_barrier(0);
            #pragma unroll
            for (int nt = 0; nt < 8; ++nt) {
                union { uint4 q_; short8x s_; } wf; wf.q_ = F[(8 + nt) * 64 + lane];
                f32x4 z = {0.f, 0.f, 0.f, 0.f};
                const f32x4 c = __builtin_amdgcn_mfma_f32_16x16x32_bf16(xf.s_, wf.s_, z, 0, 0, 0);
                #pragma unroll
                for (int rq = 0; rq < 4; ++rq)
                    hs[(4 * g4 + rq) * 132 + nt * 16 + ln] = f2bf(fmaxf(c[rq] + b1v[nt], 0.f));
            }
            asm volatile("s_waitcnt lgkmcnt(0)" ::: "memory");
            __builtin_amdgcn_sched_barrier(0);
            #pragma unroll
            for (int nt2 = 0; nt2 < 2; ++nt2) {
                f32x4 a = {0.f, 0.f, 0.f, 0.f};
                #pragma unroll
                for (int kq = 0; kq < 4; ++kq) {
                    union { unsigned short e[8]; short8x s_; } pa;
                    #pragma unroll
                    for (int j = 0; j < 8; ++j)
                        pa.e[j] = hs[ln * 132 + 32 * kq + (j & 3) + 4 * g4 + 16 * (j >> 2)];
                    union { uint4 q_; short8x s_; } w2f; w2f.q_ = F[(16 + nt2 * 4 + kq) * 64 + lane];
                    a = __builtin_amdgcn_mfma_f32_16x16x32_bf16(pa.s_, w2f.s_, a, 0, 0, 0);
                }
                #pragma unroll
                for (int r = 0; r < 4; ++r) {
                    const int t = 16 * tt + 4 * g4 + r, col = nt2 * 16 + ln;
                    out[(blk * 128 + t) * 32 + col] =
                        a[r] + (nt2 ? b2v1 : b2v0) + bf2f(kS[t * 36 + col]);
                }
            }
        }
    }
}

// ---------------------------------------------------------------- launch
extern "C" void kernel_launch(void* const* d_in, const int* in_sizes, int n_in,
                              void* d_out, int out_size, void* d_ws, size_t ws_size,
                              hipStream_t stream) {
    const float* x   = (const float*)d_in[0];
    const float* Wq  = (const float*)d_in[1];
    const float* Wk  = (const float*)d_in[2];
    const float* Wv  = (const float*)d_in[3];
    const float* Wo  = (const float*)d_in[4];
    const float* bo  = (const float*)d_in[5];
    const float* W1  = (const float*)d_in[6];
    const float* b1  = (const float*)d_in[7];
    const float* W2  = (const float*)d_in[8];
    const float* b2  = (const float*)d_in[9];
    const float* g1  = (const float*)d_in[10];
    const float* be1 = (const float*)d_in[11];
    const float* g2  = (const float*)d_in[12];
    const float* be2 = (const float*)d_in[13];
    float* outp = (float*)d_out;
    uint4* F = (uint4*)d_ws;

    hipLaunchKernelGGL(setup_frags, dim3(6), dim3(256), 0, stream,
                       Wq, Wk, Wv, Wo, W1, W2, F);
    hipLaunchKernelGGL(fused_block, dim3(2048), dim3(256), 0, stream,
                       x, bo, b1, b2, g1, be1, g2, be2, F, outp);
}